// Round 8
// baseline (550.151 us; speedup 1.0000x reference)
//
#include <hip/hip_runtime.h>
#include <cstdint>
#include <cstddef>

typedef unsigned int  uint;
typedef unsigned short ushort;

#define N_NODES 50000
#define N_EDGES 1600000
#define N_META  3
#define DIM     128

#define BKT       256                 // dst nodes per bucket
#define NBKT      196                 // ceil(N_NODES / BKT)
#define BIN_CHUNK 16384
#define NCHUNK    98                  // ceil(N_EDGES / BIN_CHUNK)
#define CSR_CAP   10240               // bucket mean 8192, +22 sigma
#define CONV_B    160                 // prep role block ranges
#define HIST_B    192                 // 64 per metapath
#define OCH       32                  // out-degree edge chunks
#define NRANGE    4                   // out-degree node ranges
#define ODEG_B    (OCH * NRANGE * N_META)   // 384
#define W1C_B     4                   // W1 fp32 -> bf16
#define ORANGE    12500               // nodes per out-degree range
#define RWORDS    3125                // ORANGE/4 byte-packed words (12.5KB)
#define OWORDS    12500               // 50000 nodes / 4 per uint

#define AT_TILE   64                  // attn: nodes per block
#define AT_NBLK   782                 // ceil(N_NODES / AT_TILE)
#define ZROW      136                 // zN row stride in ushorts (272B, 16B-aligned)

__device__ __forceinline__ uint bf16rne(float f) {
    const uint u = __float_as_uint(f);
    return (u + 0x7FFFu + ((u >> 16) & 1u)) >> 16;
}
__device__ __forceinline__ float bflo(uint p) { return __uint_as_float(p << 16); }
__device__ __forceinline__ float bfhi(uint p) { return __uint_as_float(p & 0xFFFF0000u); }

// ---------------------------------------------------------------------------
// K1: merged prep — role by block range. LDS capped at 12.8KB (12 blocks/CU).
__global__ __launch_bounds__(256) void prep_kernel(
        const float* __restrict__ h, const int* __restrict__ edges,
        const float* __restrict__ W1, ushort* __restrict__ hb,
        int* __restrict__ bucket_cnt, uint* __restrict__ partials,
        ushort* __restrict__ W1b) {
    __shared__ uint sh[RWORDS + 75];          // 12.8KB union
    const int blk = blockIdx.x;
    if (blk < CONV_B) {
        const int total = N_NODES * DIM / 4;
        for (int i = blk * 256 + threadIdx.x; i < total; i += CONV_B * 256) {
            const float4 v = reinterpret_cast<const float4*>(h)[i];
            uint2 o;
            o.x = bf16rne(v.x) | (bf16rne(v.y) << 16);
            o.y = bf16rne(v.z) | (bf16rne(v.w) << 16);
            reinterpret_cast<uint2*>(hb)[i] = o;
        }
    } else if (blk < CONV_B + HIST_B) {
        const int b2 = blk - CONV_B;
        const int m = b2 >> 6, c = b2 & 63;
        for (int j = threadIdx.x; j < NBKT; j += 256) sh[j] = 0;
        __syncthreads();
        const int* dst = edges + (size_t)(2 * m + 1) * N_EDGES;
        const int beg = c * (N_EDGES / 64);
        for (int i = beg + threadIdx.x; i < beg + (N_EDGES / 64); i += 256)
            atomicAdd(&sh[dst[i] >> 8], 1u);
        __syncthreads();
        for (int j = threadIdx.x; j < NBKT; j += 256)
            if (sh[j]) atomicAdd(&bucket_cnt[m * NBKT + j], (int)sh[j]);
    } else if (blk < CONV_B + HIST_B + ODEG_B) {
        const int b3 = blk - CONV_B - HIST_B;     // 0..383
        const int m   = b3 >> 7;                  // 128 blocks per metapath
        const int rem = b3 & 127;
        const int c   = rem >> 2;                 // chunk 0..31
        const int r   = rem & 3;                  // range 0..3
        for (int j = threadIdx.x; j < RWORDS; j += 256) sh[j] = 0;
        __syncthreads();
        const int* src = edges + (size_t)(2 * m) * N_EDGES;
        const int beg = c * (N_EDGES / OCH);
        const int rbase = r * ORANGE;
        for (int i = beg + threadIdx.x; i < beg + (N_EDGES / OCH); i += 256) {
            const unsigned u = (unsigned)(src[i] - rbase);
            if (u < (unsigned)ORANGE)
                atomicAdd(&sh[u >> 2], 1u << (8 * (u & 3)));
        }
        __syncthreads();
        uint* out = partials + (size_t)(m * OCH + c) * OWORDS + r * RWORDS;
        for (int j = threadIdx.x; j < RWORDS; j += 256) out[j] = sh[j];
    } else {
        const int local = blk - CONV_B - HIST_B - ODEG_B;
        const int base = local * (DIM * DIM / W1C_B);
        for (int i = base + threadIdx.x; i < base + DIM * DIM / W1C_B; i += 256)
            W1b[i] = (ushort)bf16rne(W1[i]);
    }
}

// ---------------------------------------------------------------------------
// K2: merged bucket scan (3 blocks, serial over 196) + nsrc merge.
__global__ __launch_bounds__(1024) void scan_nsrc_kernel(
        const int* __restrict__ bucket_cnt, int* __restrict__ bucket_off,
        int* __restrict__ bucket_cur, int* __restrict__ row_off,
        const uint* __restrict__ partials, float* __restrict__ nsrc) {
    const int blk = blockIdx.x;
    if (blk < N_META) {
        if (threadIdx.x == 0) {
            const int m = blk;
            int acc = 0;
            for (int b = 0; b < NBKT; ++b) {
                bucket_off[m * (NBKT + 1) + b] = acc;
                bucket_cur[m * NBKT + b] = acc;
                acc += bucket_cnt[m * NBKT + b];
            }
            bucket_off[m * (NBKT + 1) + NBKT] = acc;      // == N_EDGES
            row_off[m * (N_NODES + 1) + N_NODES] = N_EDGES;
        }
    } else {
        const int i = (blk - N_META) * 1024 + threadIdx.x;
        if (i < N_META * N_NODES) {
            const int m = i / N_NODES, node = i - m * N_NODES;
            const int q = node >> 2, s8 = 8 * (node & 3);
            int s = 0;
#pragma unroll
            for (int c = 0; c < OCH; ++c)
                s += (partials[(size_t)(m * OCH + c) * OWORDS + q] >> s8) & 0xFF;
            nsrc[i] = rsqrtf(fmaxf((float)s, 1.0f));
        }
    }
}

// ---------------------------------------------------------------------------
// K3: bin edges into dst-buckets as packed (dst<<16|src) pairs.
__global__ __launch_bounds__(256) void bin_kernel(
        const int* __restrict__ edges, int* __restrict__ bucket_cur,
        uint* __restrict__ pairs) {
    const int m = blockIdx.y;
    __shared__ int hist[NBKT];
    __shared__ int cur[NBKT];
    for (int j = threadIdx.x; j < NBKT; j += 256) hist[j] = 0;
    __syncthreads();
    const int* src = edges + (size_t)(2 * m) * N_EDGES;
    const int* dst = edges + (size_t)(2 * m + 1) * N_EDGES;
    const int beg = blockIdx.x * BIN_CHUNK;
    const int end = min(beg + BIN_CHUNK, N_EDGES);
    for (int i = beg + threadIdx.x; i < end; i += 256)
        atomicAdd(&hist[dst[i] >> 8], 1);
    __syncthreads();
    for (int j = threadIdx.x; j < NBKT; j += 256) {
        const int n = hist[j];
        cur[j] = n ? atomicAdd(&bucket_cur[m * NBKT + j], n) : 0;
    }
    __syncthreads();
    uint* pm = pairs + (size_t)m * N_EDGES;
    for (int i = beg + threadIdx.x; i < end; i += 256) {
        const uint d = (uint)dst[i];
        const int pos = atomicAdd(&cur[d >> 8], 1);
        pm[pos] = (d << 16) | (uint)src[i];
    }
}

// ---------------------------------------------------------------------------
// K4: finalize CSR per bucket (ushort src ids).
__global__ __launch_bounds__(256) void csr_kernel(
        const uint* __restrict__ pairs, const int* __restrict__ bucket_off,
        int* __restrict__ row_off, ushort* __restrict__ csr) {
    const int b = blockIdx.x, m = blockIdx.y;
    const int node_base = b * BKT;
    const int nb = min(BKT, N_NODES - node_base);
    __shared__ uint stage[CSR_CAP];
    __shared__ int hist[BKT];
    __shared__ int sc[BKT];
    __shared__ int cur[BKT];
    hist[threadIdx.x] = 0;
    __syncthreads();
    const int beg = bucket_off[m * (NBKT + 1) + b];
    const int end = bucket_off[m * (NBKT + 1) + b + 1];
    const int cnt = end - beg;
    const uint* pm = pairs + (size_t)m * N_EDGES + beg;
    for (int i = threadIdx.x; i < cnt; i += 256) {
        const uint p = pm[i];
        if (i < CSR_CAP) stage[i] = p;
        atomicAdd(&hist[(int)(p >> 16) - node_base], 1);
    }
    __syncthreads();
    const int v = hist[threadIdx.x];
    sc[threadIdx.x] = v;
    __syncthreads();
    for (int off = 1; off < BKT; off <<= 1) {
        const int t = (threadIdx.x >= off) ? sc[threadIdx.x - off] : 0;
        __syncthreads();
        sc[threadIdx.x] += t;
        __syncthreads();
    }
    const int excl = sc[threadIdx.x] - v;
    cur[threadIdx.x] = beg + excl;
    if (threadIdx.x < nb)
        row_off[m * (N_NODES + 1) + node_base + threadIdx.x] = beg + excl;
    __syncthreads();
    ushort* cm = csr + (size_t)m * N_EDGES;
    for (int i = threadIdx.x; i < cnt; i += 256) {
        const uint p = (i < CSR_CAP) ? stage[i] : pm[i];
        const int dl = (int)(p >> 16) - node_base;
        const int pos = atomicAdd(&cur[dl], 1);
        cm[pos] = (ushort)(p & 0xFFFFu);
    }
}

// ---------------------------------------------------------------------------
// K5: gather (bf16 h). One wave per dst node; half-wave covers a full 256B
// bf16 row, wave runs 2 edges/step, unroll-8 -> 16 edges in flight.
__global__ __launch_bounds__(256) void gather_kernel(
        const ushort* __restrict__ hb, const ushort* __restrict__ csr,
        const int* __restrict__ row_off, const float* __restrict__ nsrc,
        float* __restrict__ z) {
    const int m    = blockIdx.y;
    const int wave = threadIdx.x >> 6;
    const int lane = threadIdx.x & 63;
    const int half = lane >> 5;
    const int c    = lane & 31;              // dims 4c..4c+3
    const int node = blockIdx.x * 4 + wave;
    const int* ro = row_off + m * (N_NODES + 1);
    const int beg = ro[node];
    const int end = ro[node + 1];
    const ushort* srcs = csr + (size_t)m * N_EDGES;
    const float* ns = nsrc + m * N_NODES;
    float4 acc = {0.f, 0.f, 0.f, 0.f};
    int j = beg;
    for (; j + 16 <= end; j += 16) {
        int s[8]; float n[8]; uint2 hv[8];
#pragma unroll
        for (int u = 0; u < 8; ++u) s[u] = srcs[j + 2 * u + half];
#pragma unroll
        for (int u = 0; u < 8; ++u) {
            n[u]  = ns[s[u]];
            hv[u] = *reinterpret_cast<const uint2*>(hb + (size_t)s[u] * DIM + c * 4);
        }
#pragma unroll
        for (int u = 0; u < 8; ++u) {
            acc.x = fmaf(bflo(hv[u].x), n[u], acc.x);
            acc.y = fmaf(bfhi(hv[u].x), n[u], acc.y);
            acc.z = fmaf(bflo(hv[u].y), n[u], acc.z);
            acc.w = fmaf(bfhi(hv[u].y), n[u], acc.w);
        }
    }
    for (; j + 2 <= end; j += 2) {
        const int s0 = srcs[j + half];
        const float n0 = ns[s0];
        const uint2 h0 = *reinterpret_cast<const uint2*>(hb + (size_t)s0 * DIM + c * 4);
        acc.x = fmaf(bflo(h0.x), n0, acc.x);
        acc.y = fmaf(bfhi(h0.x), n0, acc.y);
        acc.z = fmaf(bflo(h0.y), n0, acc.z);
        acc.w = fmaf(bfhi(h0.y), n0, acc.w);
    }
    if (j < end && half == 0) {
        const int s0 = srcs[j];
        const float n0 = ns[s0];
        const uint2 h0 = *reinterpret_cast<const uint2*>(hb + (size_t)s0 * DIM + c * 4);
        acc.x = fmaf(bflo(h0.x), n0, acc.x);
        acc.y = fmaf(bfhi(h0.x), n0, acc.y);
        acc.z = fmaf(bflo(h0.y), n0, acc.z);
        acc.w = fmaf(bfhi(h0.y), n0, acc.w);
    }
    acc.x += __shfl_xor(acc.x, 32);
    acc.y += __shfl_xor(acc.y, 32);
    acc.z += __shfl_xor(acc.z, 32);
    acc.w += __shfl_xor(acc.w, 32);
    if (half == 0) {
        const float nd = rsqrtf(fmaxf((float)(end - beg), 1.0f));
        float4 o;
        o.x = acc.x * nd; o.y = acc.y * nd; o.z = acc.z * nd; o.w = acc.w * nd;
        *reinterpret_cast<float4*>(
            z + ((size_t)m * N_NODES + node) * DIM + c * 4) = o;
    }
}

// ---------------------------------------------------------------------------
// K6: semantic attention, LDS-tiled. Block = 64 nodes x 128 cols.
// zN is ROW-major bf16 (stride 272B): staging is one uint2 per thread,
// consecutive lanes 8B apart (2-way bank aliasing = free, no 16-way conflict).
// Main loop: thread = 8 nodes x 4 cols; zN reads are half-wave broadcast.
__global__ __launch_bounds__(256) void attn_kernel(
        const float* __restrict__ z, const ushort* __restrict__ W1b,
        const float* __restrict__ b1, const float* __restrict__ W2,
        float* __restrict__ wacc) {
    const int m   = blockIdx.y;
    const int tid = threadIdx.x;
    __shared__ ushort zN[AT_TILE * ZROW];      // [n][d] bf16, row stride 136
    __shared__ ushort w1s[DIM * DIM];          // [d][j] bf16
    __shared__ float red[4];

    // stage W1b (32KB) as uint4
    {
        const uint4* s = reinterpret_cast<const uint4*>(W1b);
        uint4* dst = reinterpret_cast<uint4*>(w1s);
        for (int i = tid; i < DIM * DIM / 8; i += 256) dst[i] = s[i];
    }
    // stage z tile row-major -> bf16 (uint2 = 4 bf16 per thread-iter)
    const int node_base = blockIdx.x * AT_TILE;
    {
        const float4* zf = reinterpret_cast<const float4*>(z + (size_t)m * N_NODES * DIM);
        for (int i = tid; i < AT_TILE * (DIM / 4); i += 256) {
            const int n = i >> 5, dq = i & 31;
            int row = node_base + n;
            if (row >= N_NODES) row = N_NODES - 1;
            const float4 v = zf[(size_t)row * (DIM / 4) + dq];
            uint2 o;
            o.x = bf16rne(v.x) | (bf16rne(v.y) << 16);
            o.y = bf16rne(v.z) | (bf16rne(v.w) << 16);
            *reinterpret_cast<uint2*>(&zN[n * ZROW + dq * 4]) = o;
        }
    }
    __syncthreads();

    const int jb = (tid & 31) * 4;             // 4 output cols
    const int nb = (tid >> 5) * 8;             // 8 nodes
    float q[8][4] = {};
    for (int d = 0; d < DIM; d += 8) {
        // W1 block: 8 d-rows x 4 cols
        float wv[8][4];
#pragma unroll
        for (int dd = 0; dd < 8; ++dd) {
            const uint2 wp = *reinterpret_cast<const uint2*>(&w1s[(d + dd) * DIM + jb]);
            wv[dd][0] = bflo(wp.x); wv[dd][1] = bfhi(wp.x);
            wv[dd][2] = bflo(wp.y); wv[dd][3] = bfhi(wp.y);
        }
#pragma unroll
        for (int n = 0; n < 8; ++n) {
            const uint4 zp = *reinterpret_cast<const uint4*>(&zN[(nb + n) * ZROW + d]);
            float zv[8];
            zv[0] = bflo(zp.x); zv[1] = bfhi(zp.x);
            zv[2] = bflo(zp.y); zv[3] = bfhi(zp.y);
            zv[4] = bflo(zp.z); zv[5] = bfhi(zp.z);
            zv[6] = bflo(zp.w); zv[7] = bfhi(zp.w);
#pragma unroll
            for (int dd = 0; dd < 8; ++dd) {
                q[n][0] = fmaf(zv[dd], wv[dd][0], q[n][0]);
                q[n][1] = fmaf(zv[dd], wv[dd][1], q[n][1]);
                q[n][2] = fmaf(zv[dd], wv[dd][2], q[n][2]);
                q[n][3] = fmaf(zv[dd], wv[dd][3], q[n][3]);
            }
        }
    }
    const float4 bv  = *reinterpret_cast<const float4*>(b1 + jb);
    const float4 w2v = *reinterpret_cast<const float4*>(W2 + jb);
    float local = 0.0f;
#pragma unroll
    for (int n = 0; n < 8; ++n) {
        if (node_base + nb + n < N_NODES) {
            local += tanhf(q[n][0] + bv.x) * w2v.x;
            local += tanhf(q[n][1] + bv.y) * w2v.y;
            local += tanhf(q[n][2] + bv.z) * w2v.z;
            local += tanhf(q[n][3] + bv.w) * w2v.w;
        }
    }
    for (int off = 32; off > 0; off >>= 1)
        local += __shfl_xor(local, off);
    const int wv_id = tid >> 6;
    if ((tid & 63) == 0) red[wv_id] = local;
    __syncthreads();
    if (tid == 0)
        atomicAdd(&wacc[m], red[0] + red[1] + red[2] + red[3]);
}

// ---------------------------------------------------------------------------
// K7: softmax over 3 scores + beta-weighted sum.
__global__ __launch_bounds__(256) void final_kernel(
        const float* __restrict__ z, const float* __restrict__ wacc,
        float* __restrict__ out) {
    const int g = blockIdx.x * 256 + threadIdx.x;      // float4 index
    if (g >= N_NODES * DIM / 4) return;
    const float invN = 1.0f / (float)N_NODES;
    const float w0 = wacc[0] * invN, w1 = wacc[1] * invN, w2 = wacc[2] * invN;
    const float mx = fmaxf(w0, fmaxf(w1, w2));
    const float e0 = expf(w0 - mx), e1 = expf(w1 - mx), e2 = expf(w2 - mx);
    const float inv = 1.0f / (e0 + e1 + e2);
    const float beta[3] = {e0 * inv, e1 * inv, e2 * inv};
    float4 acc = {0.f, 0.f, 0.f, 0.f};
#pragma unroll
    for (int m = 0; m < N_META; ++m) {
        const float4 zv = *reinterpret_cast<const float4*>(
            z + ((size_t)m * N_NODES) * DIM + (size_t)g * 4);
        acc.x = fmaf(zv.x, beta[m], acc.x);
        acc.y = fmaf(zv.y, beta[m], acc.y);
        acc.z = fmaf(zv.z, beta[m], acc.z);
        acc.w = fmaf(zv.w, beta[m], acc.w);
    }
    *reinterpret_cast<float4*>(out + (size_t)g * 4) = acc;
}

extern "C" void kernel_launch(void* const* d_in, const int* in_sizes, int n_in,
                              void* d_out, int out_size, void* d_ws, size_t ws_size,
                              hipStream_t stream) {
    const float* h    = (const float*)d_in[0];
    const int*  edges = (const int*)d_in[1];
    const float* W1   = (const float*)d_in[2];
    const float* b1   = (const float*)d_in[3];
    const float* W2   = (const float*)d_in[4];
    float* out = (float*)d_out;

    // ws (~100MB): z[76.8MB] region hosts pairs[19.2MB]+partials[4.8MB] early
    // (both dead before gather writes z) | hb | csr | row_off | nsrc | small
    char* p = (char*)d_ws;
    float* z        = (float*)p;
    uint*  pairs    = (uint*)p;
    uint*  partials = (uint*)(p + (size_t)N_META * N_EDGES * 4);
    p += (size_t)N_META * N_NODES * DIM * 4;
    ushort* hb      = (ushort*)p; p += (size_t)N_NODES * DIM * 2;
    ushort* csr     = (ushort*)p; p += (size_t)N_META * N_EDGES * 2;
    int* row_off    = (int*)p;    p += ((size_t)N_META * (N_NODES + 1) + 1) * 4;
    float* nsrc     = (float*)p;  p += (size_t)N_META * N_NODES * 4;
    float* wacc     = (float*)p;  p += 16 * 4;
    int* bucket_cnt = (int*)p;    p += (size_t)N_META * NBKT * 4;
    int* bucket_off = (int*)p;    p += (size_t)N_META * (NBKT + 1) * 4 + 4;
    int* bucket_cur = (int*)p;    p += (size_t)N_META * NBKT * 4;
    ushort* W1b     = (ushort*)p; p += (size_t)DIM * DIM * 2;

    // zero wacc + bucket_cnt (contiguous)
    hipMemsetAsync(wacc, 0, (16 + (size_t)N_META * NBKT) * 4, stream);

    prep_kernel<<<dim3(CONV_B + HIST_B + ODEG_B + W1C_B), 256, 0, stream>>>(
        h, edges, W1, hb, bucket_cnt, partials, W1b);
    scan_nsrc_kernel<<<dim3(N_META + (N_META * N_NODES + 1023) / 1024), 1024, 0, stream>>>(
        bucket_cnt, bucket_off, bucket_cur, row_off, partials, nsrc);
    bin_kernel<<<dim3(NCHUNK, N_META), 256, 0, stream>>>(edges, bucket_cur, pairs);
    csr_kernel<<<dim3(NBKT, N_META), 256, 0, stream>>>(pairs, bucket_off, row_off, csr);
    gather_kernel<<<dim3(N_NODES / 4, N_META), 256, 0, stream>>>(
        hb, csr, row_off, nsrc, z);
    attn_kernel<<<dim3(AT_NBLK, N_META), 256, 0, stream>>>(z, W1b, b1, W2, wacc);
    final_kernel<<<dim3((N_NODES * DIM / 4 + 255) / 256), 256, 0, stream>>>(z, wacc, out);
}